// Round 2
// baseline (193.221 us; speedup 1.0000x reference)
//
#include <hip/hip_runtime.h>
#include <hip/hip_bf16.h>
#include <stdint.h>

// Problem constants: B=4, CIN=COUT=256, H=W=64, 3x3, pad=1, stride=1, dil=1
#define KDIM 2304   // CIN * 9, GEMM K
#define KSPL 576    // KDIM / 4 split-K chunk

typedef __bf16 bf16_t;
typedef bf16_t bf16x8 __attribute__((ext_vector_type(8)));
typedef float f32x4 __attribute__((ext_vector_type(4)));
typedef float f32x2 __attribute__((ext_vector_type(2)));

__device__ __forceinline__ float b2f_lo(uint32_t u) {
  union { uint32_t i; float f; } c; c.i = u << 16; return c.f;
}
__device__ __forceinline__ float b2f_hi(uint32_t u) {
  union { uint32_t i; float f; } c; c.i = u & 0xffff0000u; return c.f;
}
// pack 2 floats -> 2 bf16 (RNE), a in low half
__device__ __forceinline__ uint32_t pk_bf16(float a, float b) {
  __hip_bfloat162 h = __float22bfloat162_rn(make_float2(a, b));
  union { __hip_bfloat162 h; uint32_t u; } c; c.h = h; return c.u;
}

// async 16B global -> LDS (wave-uniform base + lane*16 contract)
__device__ __forceinline__ void g2lds16(const uint16_t* g, uint16_t* l) {
  __builtin_amdgcn_global_load_lds((const __attribute__((address_space(1))) void*)g,
                                   (__attribute__((address_space(3))) void*)l,
                                   16, 0, 0);
}

// ---------------- kernel 1: x [4][256][64][64] f32 -> xt [4][64][64][256] bf16
__global__ __launch_bounds__(256) void k_transpose(const float* __restrict__ x,
                                                   uint16_t* __restrict__ xt) {
  __shared__ float tile[32][33];
  int b = blockIdx.z;
  int c0 = blockIdx.y << 5;
  int s0 = blockIdx.x << 5;   // s = h*64+w
  int tid = threadIdx.x;
  int tx = tid & 31, ty = tid >> 5;
  const float* src = x + ((size_t)(b * 256 + c0)) * 4096 + s0;
#pragma unroll
  for (int i = 0; i < 4; ++i)
    tile[ty + i * 8][tx] = src[(size_t)(ty + i * 8) * 4096 + tx];  // [chan][spatial]
  __syncthreads();
  int cg = tid & 7, sp = tid >> 3;
  uint2 o;
  o.x = pk_bf16(tile[cg * 4 + 0][sp], tile[cg * 4 + 1][sp]);
  o.y = pk_bf16(tile[cg * 4 + 2][sp], tile[cg * 4 + 3][sp]);
  *(uint2*)&xt[((size_t)b * 4096 + s0 + sp) * 256 + c0 + cg * 4] = o;
}

// ---------------- kernel 2: weight [256][256][3][3] f32 -> wt [cout][k*256+c] bf16
__global__ __launch_bounds__(256) void k_wprep(const float* __restrict__ w,
                                               uint16_t* __restrict__ wt) {
  int t = blockIdx.x * 256 + threadIdx.x;   // exactly 256*2304 threads
  int cout = t / KDIM;
  int r = t - cout * KDIM;
  int k = r >> 8, c = r & 255;
  wt[t] = (uint16_t)(pk_bf16(w[((size_t)(cout * 256 + c)) * 9 + k], 0.f) & 0xffffu);
}

// ---------------- kernel 3: bilinear-deform im2col -> cols [n][k*256+c] bf16
// 512 blocks = (b, ho, wo-half); 512 threads = 8 waves.
// Each wave iteration: 2 samples, 32 lanes each, 8 channels/lane (uint4 loads).
__global__ __launch_bounds__(512) void k_im2col(const uint16_t* __restrict__ xt,
                                                const float* __restrict__ off,
                                                const float* __restrict__ msk,
                                                uint16_t* __restrict__ cols) {
  __shared__ float s_off[18 * 32];
  __shared__ float s_msk[9 * 32];
  int blk = blockIdx.x;
  int wh = blk & 1;
  int ho = (blk >> 1) & 63;
  int b = blk >> 7;
  int w0 = wh << 5;
  int tid = threadIdx.x;
  for (int i = tid; i < 18 * 32; i += 512) {
    int ch = i >> 5, woi = i & 31;
    s_off[i] = off[((size_t)(b * 18 + ch)) * 4096 + ho * 64 + w0 + woi];
  }
  for (int i = tid; i < 9 * 32; i += 512) {
    int ch = i >> 5, woi = i & 31;
    s_msk[i] = msk[((size_t)(b * 9 + ch)) * 4096 + ho * 64 + w0 + woi];
  }
  __syncthreads();
  int wv = tid >> 6, lane = tid & 63;
  int half = lane >> 5, li = lane & 31;
  int c8 = li << 3;
  const uint16_t* base = xt + (size_t)b * 4096 * 256;
  uint16_t* cbase = cols + ((size_t)b * 4096 + (size_t)ho * 64 + w0) * KDIM;
  for (int p = wv; p < 144; p += 8) {
    int s = 2 * p + half;        // 0..287 = k*32 + woi
    int k = s >> 5, woi = s & 31;
    int kh = k / 3, kw = k - kh * 3;
    float dy = s_off[(2 * k) * 32 + woi];
    float dx = s_off[(2 * k + 1) * 32 + woi];
    float mm = s_msk[k * 32 + woi];
    float sy = (float)(ho - 1 + kh) + dy;
    float sx = (float)(w0 + woi - 1 + kw) + dx;
    float fy = floorf(sy), fx = floorf(sx);
    int y0 = (int)fy, x0 = (int)fx;
    float wy = sy - fy, wx = sx - fx;
    f32x2 a0 = {0.f, 0.f}, a1 = {0.f, 0.f}, a2 = {0.f, 0.f}, a3 = {0.f, 0.f};
#pragma unroll
    for (int cy = 0; cy < 2; ++cy) {
#pragma unroll
      for (int cx = 0; cx < 2; ++cx) {
        int y = y0 + cy, x = x0 + cx;
        float w = (cy ? wy : 1.f - wy) * (cx ? wx : 1.f - wx);
        bool v = ((unsigned)y < 64u) && ((unsigned)x < 64u);
        w = v ? w : 0.f;
        int yc = min(max(y, 0), 63), xc = min(max(x, 0), 63);
        const uint4 d = *(const uint4*)(base + (((size_t)yc * 64 + xc) * 256 + c8));
        f32x2 ww = {w, w};
        a0 += ww * f32x2{b2f_lo(d.x), b2f_hi(d.x)};
        a1 += ww * f32x2{b2f_lo(d.y), b2f_hi(d.y)};
        a2 += ww * f32x2{b2f_lo(d.z), b2f_hi(d.z)};
        a3 += ww * f32x2{b2f_lo(d.w), b2f_hi(d.w)};
      }
    }
    f32x2 mm2 = {mm, mm};
    a0 *= mm2; a1 *= mm2; a2 *= mm2; a3 *= mm2;
    uint4 o;
    o.x = pk_bf16(a0.x, a0.y);
    o.y = pk_bf16(a1.x, a1.y);
    o.z = pk_bf16(a2.x, a2.y);
    o.w = pk_bf16(a3.x, a3.y);
    *(uint4*)(cbase + (size_t)woi * KDIM + k * 256 + c8) = o;
  }
}

// ---------------- kernel 4: split-K GEMM  C[m][n] += sum_k A[m][k] * B[n][k]
// A = wt [256][2304], B = cols [16384][2304]; 128x128 tile, BK=32, K split x4.
#define BM 128
#define BN 128
#define BK 32
__global__ __launch_bounds__(256) void k_gemm(const uint16_t* __restrict__ A,
                                              const uint16_t* __restrict__ Bm,
                                              const float* __restrict__ bias,
                                              float* __restrict__ out) {
  __shared__ __align__(16) uint16_t As[BM * BK];
  __shared__ __align__(16) uint16_t Bs[BN * BK];
  int tid = threadIdx.x;
  int lane = tid & 63, wv = tid >> 6;
  int wm = wv >> 1, wn = wv & 1;            // 2x2 wave grid, 64x64 each
  int m0 = blockIdx.y * BM, n0 = blockIdx.x * BN;
  int kz = blockIdx.z;
  int kbeg = kz * KSPL, kend = kbeg + KSPL;
  int q = lane >> 4, r = lane & 15;

  f32x4 acc[4][4];
#pragma unroll
  for (int i = 0; i < 4; ++i)
#pragma unroll
    for (int j = 0; j < 4; ++j) acc[i][j] = f32x4{0.f, 0.f, 0.f, 0.f};

  const uint16_t* a0p = A + (size_t)(m0 + (tid >> 2)) * KDIM + (tid & 3) * 8;
  const uint16_t* a1p = A + (size_t)(m0 + 64 + (tid >> 2)) * KDIM + (tid & 3) * 8;
  const uint16_t* b0p = Bm + (size_t)(n0 + (tid >> 2)) * KDIM + (tid & 3) * 8;
  const uint16_t* b1p = Bm + (size_t)(n0 + 64 + (tid >> 2)) * KDIM + (tid & 3) * 8;
  uint16_t* as0 = &As[tid * 8];
  uint16_t* as1 = &As[2048 + tid * 8];
  uint16_t* bs0 = &Bs[tid * 8];
  uint16_t* bs1 = &Bs[2048 + tid * 8];

  for (int k0 = kbeg; k0 < kend; k0 += BK) {
    g2lds16(a0p + k0, as0);
    g2lds16(a1p + k0, as1);
    g2lds16(b0p + k0, bs0);
    g2lds16(b1p + k0, bs1);
    __syncthreads();
    bf16x8 af[4], bfr[4];
#pragma unroll
    for (int mi = 0; mi < 4; ++mi)
      af[mi] = *(const bf16x8*)&As[(wm * 64 + mi * 16 + r) * BK + q * 8];
#pragma unroll
    for (int ni = 0; ni < 4; ++ni)
      bfr[ni] = *(const bf16x8*)&Bs[(wn * 64 + ni * 16 + r) * BK + q * 8];
#pragma unroll
    for (int mi = 0; mi < 4; ++mi)
#pragma unroll
      for (int ni = 0; ni < 4; ++ni)
        acc[mi][ni] = __builtin_amdgcn_mfma_f32_16x16x32_bf16(af[mi], bfr[ni], acc[mi][ni], 0, 0, 0);
    __syncthreads();
  }

  // epilogue: C/D layout col = lane&15 (n), row = q*4 + j (m); atomic accumulate
#pragma unroll
  for (int mi = 0; mi < 4; ++mi) {
#pragma unroll
    for (int j = 0; j < 4; ++j) {
      int m = m0 + wm * 64 + mi * 16 + q * 4 + j;
      float bv = (kz == 0) ? bias[m] : 0.f;
#pragma unroll
      for (int ni = 0; ni < 4; ++ni) {
        int n = n0 + wn * 64 + ni * 16 + r;
        int b = n >> 12, p = n & 4095;
        unsafeAtomicAdd(&out[((size_t)(b * 256 + m)) * 4096 + p], acc[mi][ni][j] + bv);
      }
    }
  }
}

extern "C" void kernel_launch(void* const* d_in, const int* in_sizes, int n_in,
                              void* d_out, int out_size, void* d_ws, size_t ws_size,
                              hipStream_t stream) {
  (void)in_sizes; (void)n_in; (void)ws_size;
  const float* x      = (const float*)d_in[0];  // [4][256][64][64]
  const float* offset = (const float*)d_in[1];  // [4][18][64][64]
  const float* mask   = (const float*)d_in[2];  // [4][9][64][64]
  const float* weight = (const float*)d_in[3];  // [256][256][3][3]
  const float* bias   = (const float*)d_in[4];  // [256]
  float* out = (float*)d_out;                   // [4][256][64][64]

  uint8_t* ws = (uint8_t*)d_ws;
  uint16_t* xt   = (uint16_t*)ws;               // 8,388,608 B : NHWC bf16
  uint16_t* wt   = (uint16_t*)(ws + 8388608);   // 1,179,648 B : [cout][k*256+c]
  uint16_t* cols = (uint16_t*)(ws + 9568256);   // 75,497,472 B: [n][k*256+c]

  hipMemsetAsync(out, 0, (size_t)out_size * sizeof(float), stream);
  k_transpose<<<dim3(128, 8, 4), 256, 0, stream>>>(x, xt);
  k_wprep<<<dim3(2304), 256, 0, stream>>>(weight, wt);
  k_im2col<<<dim3(512), 512, 0, stream>>>(xt, offset, mask, cols);
  k_gemm<<<dim3(128, 2, 4), 256, 0, stream>>>(wt, cols, bias, out);
}

// Round 3
// 141.378 us; speedup vs baseline: 1.3667x; 1.3667x over previous
//
#include <hip/hip_runtime.h>
#include <hip/hip_bf16.h>
#include <stdint.h>

// Problem constants: B=4, CIN=COUT=256, H=W=64, 3x3, pad=1, stride=1, dil=1
#define KDIM 2304   // CIN * 9, GEMM K

typedef __bf16 bf16_t;
typedef bf16_t bf16x8 __attribute__((ext_vector_type(8)));
typedef float f32x4 __attribute__((ext_vector_type(4)));
typedef float f32x2 __attribute__((ext_vector_type(2)));

__device__ __forceinline__ float b2f_lo(uint32_t u) {
  union { uint32_t i; float f; } c; c.i = u << 16; return c.f;
}
__device__ __forceinline__ float b2f_hi(uint32_t u) {
  union { uint32_t i; float f; } c; c.i = u & 0xffff0000u; return c.f;
}
// pack 2 floats -> 2 bf16 (RNE), a in low half
__device__ __forceinline__ uint32_t pk_bf16(float a, float b) {
  __hip_bfloat162 h = __float22bfloat162_rn(make_float2(a, b));
  union { __hip_bfloat162 h; uint32_t u; } c; c.h = h; return c.u;
}

// async 16B global -> LDS (wave-uniform base + lane*16 contract)
__device__ __forceinline__ void g2lds16(const uint16_t* g, uint16_t* l) {
  __builtin_amdgcn_global_load_lds((const __attribute__((address_space(1))) void*)g,
                                   (__attribute__((address_space(3))) void*)l,
                                   16, 0, 0);
}

// ---------------- kernel 1: x [4][256][64][64] f32 -> xt [4][64][64][256] bf16
__global__ __launch_bounds__(256) void k_transpose(const float* __restrict__ x,
                                                   uint16_t* __restrict__ xt) {
  __shared__ float tile[32][33];
  int b = blockIdx.z;
  int c0 = blockIdx.y << 5;
  int s0 = blockIdx.x << 5;   // s = h*64+w
  int tid = threadIdx.x;
  int tx = tid & 31, ty = tid >> 5;
  const float* src = x + ((size_t)(b * 256 + c0)) * 4096 + s0;
#pragma unroll
  for (int i = 0; i < 4; ++i)
    tile[ty + i * 8][tx] = src[(size_t)(ty + i * 8) * 4096 + tx];  // [chan][spatial]
  __syncthreads();
  int cg = tid & 7, sp = tid >> 3;
  uint2 o;
  o.x = pk_bf16(tile[cg * 4 + 0][sp], tile[cg * 4 + 1][sp]);
  o.y = pk_bf16(tile[cg * 4 + 2][sp], tile[cg * 4 + 3][sp]);
  *(uint2*)&xt[((size_t)b * 4096 + s0 + sp) * 256 + c0 + cg * 4] = o;
}

// ---------------- kernel 2: weight [256][256][3][3] f32 -> wt [cout][k*256+c] bf16
__global__ __launch_bounds__(256) void k_wprep(const float* __restrict__ w,
                                               uint16_t* __restrict__ wt) {
  int t = blockIdx.x * 256 + threadIdx.x;   // exactly 256*2304 threads
  int cout = t / KDIM;
  int r = t - cout * KDIM;
  int k = r >> 8, c = r & 255;
  wt[t] = (uint16_t)(pk_bf16(w[((size_t)(cout * 256 + c)) * 9 + k], 0.f) & 0xffffu);
}

// ---------------- kernel 3: bilinear-deform im2col -> cols [n][k*256+c] bf16
// 1024 blocks = (b, ho, wo-quarter); 256 threads = 4 waves.
// Each wave iteration: 2 samples, 32 lanes each, 8 channels/lane (uint4 loads).
__global__ __launch_bounds__(256) void k_im2col(const uint16_t* __restrict__ xt,
                                                const float* __restrict__ off,
                                                const float* __restrict__ msk,
                                                uint16_t* __restrict__ cols) {
  __shared__ float s_off[18 * 16];
  __shared__ float s_msk[9 * 16];
  int blk = blockIdx.x;
  int wq = blk & 3;
  int ho = (blk >> 2) & 63;
  int b = blk >> 8;
  int w0 = wq << 4;
  int tid = threadIdx.x;
  if (tid < 18 * 16) {
    int ch = tid >> 4, woi = tid & 15;
    s_off[tid] = off[((size_t)(b * 18 + ch)) * 4096 + ho * 64 + w0 + woi];
  } else if (tid >= 64 && tid < 64 + 9 * 16) {
    int i = tid - 64;   // overlap-free: 18*16=288 > 64? no -- guard below
  }
  // (re-stage cleanly: 288 offsets + 144 masks by 256 threads)
  __syncthreads();  // ensure s_off writes from first branch are ordered (cheap)
  for (int i = tid; i < 18 * 16; i += 256) {
    int ch = i >> 4, woi = i & 15;
    s_off[i] = off[((size_t)(b * 18 + ch)) * 4096 + ho * 64 + w0 + woi];
  }
  for (int i = tid; i < 9 * 16; i += 256) {
    int ch = i >> 4, woi = i & 15;
    s_msk[i] = msk[((size_t)(b * 9 + ch)) * 4096 + ho * 64 + w0 + woi];
  }
  __syncthreads();
  int wv = tid >> 6, lane = tid & 63;
  int half = lane >> 5, li = lane & 31;
  int c8 = li << 3;
  const uint16_t* base = xt + (size_t)b * 4096 * 256;
  uint16_t* cbase = cols + ((size_t)b * 4096 + (size_t)ho * 64 + w0) * KDIM;
  for (int p = wv; p < 72; p += 4) {
    int s = 2 * p + half;        // 0..143 = k*16 + woi
    int k = s >> 4, woi = s & 15;
    int kh = k / 3, kw = k - kh * 3;
    float dy = s_off[(2 * k) * 16 + woi];
    float dx = s_off[(2 * k + 1) * 16 + woi];
    float mm = s_msk[k * 16 + woi];
    float sy = (float)(ho - 1 + kh) + dy;
    float sx = (float)(w0 + woi - 1 + kw) + dx;
    float fy = floorf(sy), fx = floorf(sx);
    int y0 = (int)fy, x0 = (int)fx;
    float wy = sy - fy, wx = sx - fx;
    f32x2 a0 = {0.f, 0.f}, a1 = {0.f, 0.f}, a2 = {0.f, 0.f}, a3 = {0.f, 0.f};
#pragma unroll
    for (int cy = 0; cy < 2; ++cy) {
#pragma unroll
      for (int cx = 0; cx < 2; ++cx) {
        int y = y0 + cy, x = x0 + cx;
        float w = (cy ? wy : 1.f - wy) * (cx ? wx : 1.f - wx);
        bool v = ((unsigned)y < 64u) && ((unsigned)x < 64u);
        w = v ? w : 0.f;
        int yc = min(max(y, 0), 63), xc = min(max(x, 0), 63);
        const uint4 d = *(const uint4*)(base + (((size_t)yc * 64 + xc) * 256 + c8));
        f32x2 ww = {w, w};
        a0 += ww * f32x2{b2f_lo(d.x), b2f_hi(d.x)};
        a1 += ww * f32x2{b2f_lo(d.y), b2f_hi(d.y)};
        a2 += ww * f32x2{b2f_lo(d.z), b2f_hi(d.z)};
        a3 += ww * f32x2{b2f_lo(d.w), b2f_hi(d.w)};
      }
    }
    f32x2 mm2 = {mm, mm};
    a0 *= mm2; a1 *= mm2; a2 *= mm2; a3 *= mm2;
    uint4 o;
    o.x = pk_bf16(a0.x, a0.y);
    o.y = pk_bf16(a1.x, a1.y);
    o.z = pk_bf16(a2.x, a2.y);
    o.w = pk_bf16(a3.x, a3.y);
    *(uint4*)(cbase + (size_t)woi * KDIM + k * 256 + c8) = o;
  }
}

// ---------------- kernel 4: GEMM  C[m][n] = sum_k A[m][k] * B[n][k]
// A = wt [256][2304], B = cols [16384][2304]; tile 128m x 64n, BK=32.
// Grid 256x2 = 512 blocks -> 2 blocks/CU for barrier-drain overlap.
#define BM 128
#define BN 64
#define BK 32
__global__ __launch_bounds__(256) void k_gemm(const uint16_t* __restrict__ A,
                                              const uint16_t* __restrict__ Bm,
                                              const float* __restrict__ bias,
                                              float* __restrict__ out) {
  __shared__ __align__(16) uint16_t As[BM * BK];
  __shared__ __align__(16) uint16_t Bs[BN * BK];
  int tid = threadIdx.x;
  int lane = tid & 63, wv = tid >> 6;
  int wm = wv >> 1, wn = wv & 1;            // 2x2 wave grid: 64m x 32n each
  int m0 = blockIdx.y * BM, n0 = blockIdx.x * BN;
  int q = lane >> 4, r = lane & 15;

  f32x4 acc[4][2];
#pragma unroll
  for (int i = 0; i < 4; ++i)
#pragma unroll
    for (int j = 0; j < 2; ++j) acc[i][j] = f32x4{0.f, 0.f, 0.f, 0.f};

  // staging: 3 chunks of 4KB: A rows 0-63, A rows 64-127, B rows 0-63
  const uint16_t* a0p = A + (size_t)(m0 + (tid >> 2)) * KDIM + (tid & 3) * 8;
  const uint16_t* a1p = A + (size_t)(m0 + 64 + (tid >> 2)) * KDIM + (tid & 3) * 8;
  const uint16_t* b0p = Bm + (size_t)(n0 + (tid >> 2)) * KDIM + (tid & 3) * 8;
  uint16_t* as0 = &As[tid * 8];
  uint16_t* as1 = &As[2048 + tid * 8];
  uint16_t* bs0 = &Bs[tid * 8];

  for (int k0 = 0; k0 < KDIM; k0 += BK) {
    g2lds16(a0p + k0, as0);
    g2lds16(a1p + k0, as1);
    g2lds16(b0p + k0, bs0);
    __syncthreads();
    bf16x8 af[4], bfr[2];
#pragma unroll
    for (int mi = 0; mi < 4; ++mi)
      af[mi] = *(const bf16x8*)&As[(wm * 64 + mi * 16 + r) * BK + q * 8];
#pragma unroll
    for (int ni = 0; ni < 2; ++ni)
      bfr[ni] = *(const bf16x8*)&Bs[(wn * 32 + ni * 16 + r) * BK + q * 8];
#pragma unroll
    for (int mi = 0; mi < 4; ++mi)
#pragma unroll
      for (int ni = 0; ni < 2; ++ni)
        acc[mi][ni] = __builtin_amdgcn_mfma_f32_16x16x32_bf16(af[mi], bfr[ni], acc[mi][ni], 0, 0, 0);
    __syncthreads();
  }

  // epilogue: C/D layout col = lane&15 (n), row = q*4 + j (m); direct store
#pragma unroll
  for (int mi = 0; mi < 4; ++mi) {
#pragma unroll
    for (int j = 0; j < 4; ++j) {
      int m = m0 + wm * 64 + mi * 16 + q * 4 + j;
      float bv = bias[m];
#pragma unroll
      for (int ni = 0; ni < 2; ++ni) {
        int n = n0 + wn * 32 + ni * 16 + r;
        int b = n >> 12, p = n & 4095;
        out[((size_t)(b * 256 + m)) * 4096 + p] = acc[mi][ni][j] + bv;
      }
    }
  }
}

extern "C" void kernel_launch(void* const* d_in, const int* in_sizes, int n_in,
                              void* d_out, int out_size, void* d_ws, size_t ws_size,
                              hipStream_t stream) {
  (void)in_sizes; (void)n_in; (void)out_size; (void)ws_size;
  const float* x      = (const float*)d_in[0];  // [4][256][64][64]
  const float* offset = (const float*)d_in[1];  // [4][18][64][64]
  const float* mask   = (const float*)d_in[2];  // [4][9][64][64]
  const float* weight = (const float*)d_in[3];  // [256][256][3][3]
  const float* bias   = (const float*)d_in[4];  // [256]
  float* out = (float*)d_out;                   // [4][256][64][64]

  uint8_t* ws = (uint8_t*)d_ws;
  uint16_t* xt   = (uint16_t*)ws;               // 8,388,608 B : NHWC bf16
  uint16_t* wt   = (uint16_t*)(ws + 8388608);   // 1,179,648 B : [cout][k*256+c]
  uint16_t* cols = (uint16_t*)(ws + 9568256);   // 75,497,472 B: [n][k*256+c]

  k_transpose<<<dim3(128, 8, 4), 256, 0, stream>>>(x, xt);
  k_wprep<<<dim3(2304), 256, 0, stream>>>(weight, wt);
  k_im2col<<<dim3(1024), 256, 0, stream>>>(xt, offset, mask, cols);
  k_gemm<<<dim3(256, 2), 256, 0, stream>>>(wt, cols, bias, out);
}